// Round 1
// baseline (10.973 us; speedup 1.0000x reference)
//
#include <hip/hip_runtime.h>
#include <math.h>

// Shapes from the reference: (L, B, N, C) = (4, 16, 4096, 512), fp32.
// Only the last token (n = N-1) contributes.
#define L_DIM 4
#define B_DIM 16
#define N_DIM 4096
#define C_DIM 512

// One wave (64 lanes) per (l,b) row. Each lane owns 8 channels:
// two float4 loads at c = 4*t and c = 256 + 4*t (perfectly coalesced:
// each wave instruction covers 1 KiB contiguous).
__global__ __launch_bounds__(64) void kd_row_kernel(
    const float* __restrict__ g1, const float* __restrict__ g2,
    float* __restrict__ partial)
{
    const int row = blockIdx.x;            // l*B + b, 0..63
    const int t   = threadIdx.x;           // 0..63
    const size_t base = ((size_t)row * N_DIM + (N_DIM - 1)) * (size_t)C_DIM;

    const float4 a0 = *(const float4*)(g1 + base + 4 * t);
    const float4 a1 = *(const float4*)(g1 + base + 256 + 4 * t);
    const float4 b0 = *(const float4*)(g2 + base + 4 * t);
    const float4 b1 = *(const float4*)(g2 + base + 256 + 4 * t);

    float x1[8] = {a0.x, a0.y, a0.z, a0.w, a1.x, a1.y, a1.z, a1.w};
    float x2[8] = {b0.x, b0.y, b0.z, b0.w, b1.x, b1.y, b1.z, b1.w};

    float m1 = -INFINITY, m2 = -INFINITY;
    #pragma unroll
    for (int k = 0; k < 8; ++k) {
        x1[k] *= 0.5f;  x2[k] *= 0.5f;     // x = guidance / 2
        m1 = fmaxf(m1, x1[k]);
        m2 = fmaxf(m2, x2[k]);
    }
    // wave-wide max (64 lanes)
    #pragma unroll
    for (int off = 32; off > 0; off >>= 1) {
        m1 = fmaxf(m1, __shfl_xor(m1, off, 64));
        m2 = fmaxf(m2, __shfl_xor(m2, off, 64));
    }

    float s1 = 0.f, s2 = 0.f;
    #pragma unroll
    for (int k = 0; k < 8; ++k) {
        s1 += __expf(x1[k] - m1);
        s2 += __expf(x2[k] - m2);
    }
    // wave-wide sum
    #pragma unroll
    for (int off = 32; off > 0; off >>= 1) {
        s1 += __shfl_xor(s1, off, 64);
        s2 += __shfl_xor(s2, off, 64);
    }
    const float lse1 = m1 + __logf(s1);
    const float lse2 = m2 + __logf(s2);

    // sym-KL contribution: (p1 - p2) * (lp1 - lp2), summed over channels
    float acc = 0.f;
    #pragma unroll
    for (int k = 0; k < 8; ++k) {
        const float lp1 = x1[k] - lse1;
        const float lp2 = x2[k] - lse2;
        acc += (__expf(lp1) - __expf(lp2)) * (lp1 - lp2);
    }
    #pragma unroll
    for (int off = 32; off > 0; off >>= 1)
        acc += __shfl_xor(acc, off, 64);

    if (t == 0) partial[row] = acc;
}

// Reduce the 64 row partials -> scalar. out = 0.5 * mean_over_L(sum) = (0.5/L) * total
__global__ __launch_bounds__(64) void kd_final_kernel(
    const float* __restrict__ partial, float* __restrict__ out)
{
    float v = partial[threadIdx.x];
    #pragma unroll
    for (int off = 32; off > 0; off >>= 1)
        v += __shfl_xor(v, off, 64);
    if (threadIdx.x == 0)
        out[0] = v * (0.5f / (float)L_DIM);
}

extern "C" void kernel_launch(void* const* d_in, const int* in_sizes, int n_in,
                              void* d_out, int out_size, void* d_ws, size_t ws_size,
                              hipStream_t stream) {
    const float* g1 = (const float*)d_in[0];
    const float* g2 = (const float*)d_in[1];
    float* out      = (float*)d_out;
    float* partial  = (float*)d_ws;   // 64 floats of scratch

    kd_row_kernel<<<dim3(L_DIM * B_DIM), dim3(64), 0, stream>>>(g1, g2, partial);
    kd_final_kernel<<<dim3(1), dim3(64), 0, stream>>>(partial, out);
}